// Round 1
// baseline (313.049 us; speedup 1.0000x reference)
//
#include <hip/hip_runtime.h>

#define NLEVELS 8

// RESOLUTIONS = [16, 29, 53, 98, 181, 332, 610, 1120]
__constant__ int   c_res[NLEVELS]   = {16, 29, 53, 98, 181, 332, 610, 1120};
__constant__ float c_scale[NLEVELS] = {7.5f, 14.0f, 26.0f, 48.5f, 90.0f, 165.5f, 304.5f, 559.5f};
// cumulative texel offsets (sum of res^2)
__constant__ int   c_cum[NLEVELS]   = {0, 256, 1097, 3906, 13510, 46271, 156495, 528595};
#define TOTAL_TEXELS 1782995

struct CbPtrs { const float* cb[NLEVELS]; };

// ---------------- transpose [4,R,R] -> [R,R,4] (float4 texels) ----------------
__global__ __launch_bounds__(256) void transpose_cbs(CbPtrs p, float4* __restrict__ tcb, int total) {
    for (int t = blockIdx.x * blockDim.x + threadIdx.x; t < total; t += gridDim.x * blockDim.x) {
        int L = 0;
#pragma unroll
        for (int i = 1; i < NLEVELS; ++i) if (t >= c_cum[i]) L = i;
        int i  = t - c_cum[L];
        int rr = c_res[L] * c_res[L];
        const float* cb = p.cb[L];
        tcb[t] = make_float4(cb[i], cb[i + rr], cb[i + 2 * rr], cb[i + 3 * rr]);
    }
}

// ---------------- main: one thread per (sample, level), levels == 8 ----------------
__global__ __launch_bounds__(256) void grid_main(const float2* __restrict__ coords,
                                                 const float4* __restrict__ tcb,
                                                 float4* __restrict__ out4, int S) {
    int t = blockIdx.x * 256 + threadIdx.x;
    if (t >= S * 8) return;
    int L = t & 7;
    int s = t >> 3;
    float2 c = coords[s];
    int   res   = c_res[L];
    float scale = c_scale[L];
    const float4* __restrict__ base = tcb + c_cum[L];

    float px = (c.x + 1.0f) * scale;
    float py = (c.y + 1.0f) * scale;
    float x0f = floorf(px), y0f = floorf(py);
    float wx = px - x0f,    wy = py - y0f;
    int rm1 = res - 1;
    int x0 = min(max((int)x0f, 0), rm1);
    int x1 = min(x0 + 1, rm1);
    int y0 = min(max((int)y0f, 0), rm1);
    int y1 = min(y0 + 1, rm1);
    int r0 = y0 * res, r1 = y1 * res;

    float4 f00 = base[r0 + x0];
    float4 f01 = base[r0 + x1];
    float4 f10 = base[r1 + x0];
    float4 f11 = base[r1 + x1];

    float w00 = (1.0f - wx) * (1.0f - wy);
    float w01 = wx * (1.0f - wy);
    float w10 = (1.0f - wx) * wy;
    float w11 = wx * wy;

    float4 r;
    r.x = f00.x * w00 + f01.x * w01 + f10.x * w10 + f11.x * w11;
    r.y = f00.y * w00 + f01.y * w01 + f10.y * w10 + f11.y * w11;
    r.z = f00.z * w00 + f01.z * w01 + f10.z * w10 + f11.z * w11;
    r.w = f00.w * w00 + f01.w * w01 + f10.w * w10 + f11.w * w11;
    out4[t] = r;
}

// ---------------- fallback: gather directly from [4,R,R] layout ----------------
__global__ __launch_bounds__(256) void grid_main_direct(const float2* __restrict__ coords,
                                                        CbPtrs p, float4* __restrict__ out4, int S) {
    int t = blockIdx.x * 256 + threadIdx.x;
    if (t >= S * 8) return;
    int L = t & 7;
    int s = t >> 3;
    float2 c = coords[s];
    int   res   = c_res[L];
    float scale = c_scale[L];
    const float* cb = p.cb[L];

    float px = (c.x + 1.0f) * scale;
    float py = (c.y + 1.0f) * scale;
    float x0f = floorf(px), y0f = floorf(py);
    float wx = px - x0f,    wy = py - y0f;
    int rm1 = res - 1;
    int x0 = min(max((int)x0f, 0), rm1);
    int x1 = min(x0 + 1, rm1);
    int y0 = min(max((int)y0f, 0), rm1);
    int y1 = min(y0 + 1, rm1);
    int rr = res * res;
    int i00 = y0 * res + x0, i01 = y0 * res + x1, i10 = y1 * res + x0, i11 = y1 * res + x1;

    float w00 = (1.0f - wx) * (1.0f - wy);
    float w01 = wx * (1.0f - wy);
    float w10 = (1.0f - wx) * wy;
    float w11 = wx * wy;

    float4 r;
    float* pr = &r.x;
#pragma unroll
    for (int f = 0; f < 4; ++f) {
        const float* cf = cb + f * rr;
        pr[f] = cf[i00] * w00 + cf[i01] * w01 + cf[i10] * w10 + cf[i11] * w11;
    }
    out4[t] = r;
}

// ---------------- generic levels fallback (levels != 8) ----------------
__global__ __launch_bounds__(256) void grid_generic(const float2* __restrict__ coords,
                                                    CbPtrs p, const float4* __restrict__ tcb,
                                                    float4* __restrict__ out4, int S, int levels,
                                                    int useT) {
    int s = blockIdx.x * 256 + threadIdx.x;
    if (s >= S) return;
    float2 c = coords[s];
    for (int L = 0; L < levels; ++L) {
        int   res   = c_res[L];
        float scale = c_scale[L];
        float px = (c.x + 1.0f) * scale;
        float py = (c.y + 1.0f) * scale;
        float x0f = floorf(px), y0f = floorf(py);
        float wx = px - x0f,    wy = py - y0f;
        int rm1 = res - 1;
        int x0 = min(max((int)x0f, 0), rm1);
        int x1 = min(x0 + 1, rm1);
        int y0 = min(max((int)y0f, 0), rm1);
        int y1 = min(y0 + 1, rm1);
        int i00 = y0 * res + x0, i01 = y0 * res + x1, i10 = y1 * res + x0, i11 = y1 * res + x1;
        float w00 = (1.0f - wx) * (1.0f - wy);
        float w01 = wx * (1.0f - wy);
        float w10 = (1.0f - wx) * wy;
        float w11 = wx * wy;
        float4 r;
        if (useT) {
            const float4* base = tcb + c_cum[L];
            float4 f00 = base[i00], f01 = base[i01], f10 = base[i10], f11 = base[i11];
            r.x = f00.x * w00 + f01.x * w01 + f10.x * w10 + f11.x * w11;
            r.y = f00.y * w00 + f01.y * w01 + f10.y * w10 + f11.y * w11;
            r.z = f00.z * w00 + f01.z * w01 + f10.z * w10 + f11.z * w11;
            r.w = f00.w * w00 + f01.w * w01 + f10.w * w10 + f11.w * w11;
        } else {
            const float* cb = p.cb[L];
            int rr = res * res;
            float* pr = &r.x;
#pragma unroll
            for (int f = 0; f < 4; ++f) {
                const float* cf = cb + f * rr;
                pr[f] = cf[i00] * w00 + cf[i01] * w01 + cf[i10] * w10 + cf[i11] * w11;
            }
        }
        out4[(size_t)s * levels + L] = r;
    }
}

extern "C" void kernel_launch(void* const* d_in, const int* in_sizes, int n_in,
                              void* d_out, int out_size, void* d_ws, size_t ws_size,
                              hipStream_t stream) {
    const float2* coords = (const float2*)d_in[0];
    int S = in_sizes[0] / 2;                 // total samples B*N
    int levels = out_size / (S * 4);         // features per sample / FEATURE_DIM

    CbPtrs ptrs;
    for (int i = 0; i < NLEVELS; ++i) ptrs.cb[i] = (const float*)d_in[2 + i];

    float4* out4 = (float4*)d_out;
    float4* tcb  = (float4*)d_ws;
    bool useT = ws_size >= (size_t)TOTAL_TEXELS * sizeof(float4);

    if (useT) {
        int tg = (TOTAL_TEXELS + 255) / 256;
        transpose_cbs<<<tg, 256, 0, stream>>>(ptrs, tcb, TOTAL_TEXELS);
    }

    if (levels == NLEVELS) {
        int total  = S * 8;
        int blocks = (total + 255) / 256;
        if (useT)
            grid_main<<<blocks, 256, 0, stream>>>(coords, tcb, out4, S);
        else
            grid_main_direct<<<blocks, 256, 0, stream>>>(coords, ptrs, out4, S);
    } else {
        int blocks = (S + 255) / 256;
        grid_generic<<<blocks, 256, 0, stream>>>(coords, ptrs, tcb, out4, S, levels, useT ? 1 : 0);
    }
}

// Round 2
// 281.835 us; speedup vs baseline: 1.1108x; 1.1108x over previous
//
#include <hip/hip_runtime.h>
#include <hip/hip_fp16.h>

#define NLEVELS 8

// RESOLUTIONS = [16, 29, 53, 98, 181, 332, 610, 1120]
__constant__ int   c_res[NLEVELS]   = {16, 29, 53, 98, 181, 332, 610, 1120};
__constant__ float c_scale[NLEVELS] = {7.5f, 14.0f, 26.0f, 48.5f, 90.0f, 165.5f, 304.5f, 559.5f};
// cumulative texel offsets (sum of res^2)
__constant__ int   c_cum[NLEVELS]   = {0, 256, 1097, 3906, 13510, 46271, 156495, 528595};
#define TOTAL_TEXELS 1782995

typedef float f32x4 __attribute__((ext_vector_type(4)));

struct CbPtrs { const float* cb[NLEVELS]; };

__device__ __forceinline__ float2 up_h2(unsigned int v) {
    __half2 h = *reinterpret_cast<__half2*>(&v);
    return __half22float2(h);
}

// ---------------- transpose [4,R,R] fp32 -> [R,R,4] fp16 texels (8B uint2) ----------------
__global__ __launch_bounds__(256) void transpose_cbs(CbPtrs p, uint2* __restrict__ tcb, int total) {
    for (int t = blockIdx.x * blockDim.x + threadIdx.x; t < total; t += gridDim.x * blockDim.x) {
        int L = 0;
#pragma unroll
        for (int i = 1; i < NLEVELS; ++i) if (t >= c_cum[i]) L = i;
        int i  = t - c_cum[L];
        int rr = c_res[L] * c_res[L];
        const float* cb = p.cb[L];
        __half2 h01 = __floats2half2_rn(cb[i],          cb[i + rr]);
        __half2 h23 = __floats2half2_rn(cb[i + 2 * rr], cb[i + 3 * rr]);
        uint2 tex;
        tex.x = *reinterpret_cast<unsigned int*>(&h01);
        tex.y = *reinterpret_cast<unsigned int*>(&h23);
        tcb[t] = tex;
    }
}

// ---------------- main: one thread per (sample, level), levels == 8 ----------------
__global__ __launch_bounds__(256) void grid_main(const float2* __restrict__ coords,
                                                 const uint2* __restrict__ tcb,
                                                 f32x4* __restrict__ out4, int S) {
    int t = blockIdx.x * 256 + threadIdx.x;
    if (t >= S * 8) return;
    int L = t & 7;
    int s = t >> 3;
    float2 c = coords[s];
    int   res   = c_res[L];
    float scale = c_scale[L];
    const uint2* __restrict__ base = tcb + c_cum[L];

    float px = (c.x + 1.0f) * scale;
    float py = (c.y + 1.0f) * scale;
    float x0f = floorf(px), y0f = floorf(py);
    float wx = px - x0f,    wy = py - y0f;
    int rm1 = res - 1;
    int x0 = min(max((int)x0f, 0), rm1);
    int x1 = min(x0 + 1, rm1);
    int y0 = min(max((int)y0f, 0), rm1);
    int y1 = min(y0 + 1, rm1);
    int r0 = y0 * res, r1 = y1 * res;

    uint2 t00 = base[r0 + x0];
    uint2 t01 = base[r0 + x1];
    uint2 t10 = base[r1 + x0];
    uint2 t11 = base[r1 + x1];

    float w00 = (1.0f - wx) * (1.0f - wy);
    float w01 = wx * (1.0f - wy);
    float w10 = (1.0f - wx) * wy;
    float w11 = wx * wy;

    float2 a00 = up_h2(t00.x), b00 = up_h2(t00.y);
    float2 a01 = up_h2(t01.x), b01 = up_h2(t01.y);
    float2 a10 = up_h2(t10.x), b10 = up_h2(t10.y);
    float2 a11 = up_h2(t11.x), b11 = up_h2(t11.y);

    f32x4 r;
    r.x = a00.x * w00 + a01.x * w01 + a10.x * w10 + a11.x * w11;
    r.y = a00.y * w00 + a01.y * w01 + a10.y * w10 + a11.y * w11;
    r.z = b00.x * w00 + b01.x * w01 + b10.x * w10 + b11.x * w11;
    r.w = b00.y * w00 + b01.y * w01 + b10.y * w10 + b11.y * w11;

    __builtin_nontemporal_store(r, &out4[t]);
}

// ---------------- fallback: gather directly from [4,R,R] fp32 layout ----------------
__global__ __launch_bounds__(256) void grid_main_direct(const float2* __restrict__ coords,
                                                        CbPtrs p, float4* __restrict__ out4, int S) {
    int t = blockIdx.x * 256 + threadIdx.x;
    if (t >= S * 8) return;
    int L = t & 7;
    int s = t >> 3;
    float2 c = coords[s];
    int   res   = c_res[L];
    float scale = c_scale[L];
    const float* cb = p.cb[L];

    float px = (c.x + 1.0f) * scale;
    float py = (c.y + 1.0f) * scale;
    float x0f = floorf(px), y0f = floorf(py);
    float wx = px - x0f,    wy = py - y0f;
    int rm1 = res - 1;
    int x0 = min(max((int)x0f, 0), rm1);
    int x1 = min(x0 + 1, rm1);
    int y0 = min(max((int)y0f, 0), rm1);
    int y1 = min(y0 + 1, rm1);
    int rr = res * res;
    int i00 = y0 * res + x0, i01 = y0 * res + x1, i10 = y1 * res + x0, i11 = y1 * res + x1;

    float w00 = (1.0f - wx) * (1.0f - wy);
    float w01 = wx * (1.0f - wy);
    float w10 = (1.0f - wx) * wy;
    float w11 = wx * wy;

    float4 r;
    float* pr = &r.x;
#pragma unroll
    for (int f = 0; f < 4; ++f) {
        const float* cf = cb + f * rr;
        pr[f] = cf[i00] * w00 + cf[i01] * w01 + cf[i10] * w10 + cf[i11] * w11;
    }
    out4[t] = r;
}

// ---------------- generic levels fallback (levels != 8) ----------------
__global__ __launch_bounds__(256) void grid_generic(const float2* __restrict__ coords,
                                                    CbPtrs p, float4* __restrict__ out4,
                                                    int S, int levels) {
    int s = blockIdx.x * 256 + threadIdx.x;
    if (s >= S) return;
    float2 c = coords[s];
    for (int L = 0; L < levels; ++L) {
        int   res   = c_res[L];
        float scale = c_scale[L];
        float px = (c.x + 1.0f) * scale;
        float py = (c.y + 1.0f) * scale;
        float x0f = floorf(px), y0f = floorf(py);
        float wx = px - x0f,    wy = py - y0f;
        int rm1 = res - 1;
        int x0 = min(max((int)x0f, 0), rm1);
        int x1 = min(x0 + 1, rm1);
        int y0 = min(max((int)y0f, 0), rm1);
        int y1 = min(y0 + 1, rm1);
        int i00 = y0 * res + x0, i01 = y0 * res + x1, i10 = y1 * res + x0, i11 = y1 * res + x1;
        float w00 = (1.0f - wx) * (1.0f - wy);
        float w01 = wx * (1.0f - wy);
        float w10 = (1.0f - wx) * wy;
        float w11 = wx * wy;
        float4 r;
        const float* cb = p.cb[L];
        int rr = res * res;
        float* pr = &r.x;
#pragma unroll
        for (int f = 0; f < 4; ++f) {
            const float* cf = cb + f * rr;
            pr[f] = cf[i00] * w00 + cf[i01] * w01 + cf[i10] * w10 + cf[i11] * w11;
        }
        out4[(size_t)s * levels + L] = r;
    }
}

extern "C" void kernel_launch(void* const* d_in, const int* in_sizes, int n_in,
                              void* d_out, int out_size, void* d_ws, size_t ws_size,
                              hipStream_t stream) {
    const float2* coords = (const float2*)d_in[0];
    int S = in_sizes[0] / 2;                 // total samples B*N
    int levels = out_size / (S * 4);         // features per sample / FEATURE_DIM

    CbPtrs ptrs;
    for (int i = 0; i < NLEVELS; ++i) ptrs.cb[i] = (const float*)d_in[2 + i];

    uint2* tcb = (uint2*)d_ws;
    bool useT = ws_size >= (size_t)TOTAL_TEXELS * sizeof(uint2);

    if (levels == NLEVELS && useT) {
        int tg = (TOTAL_TEXELS + 255) / 256;
        transpose_cbs<<<tg, 256, 0, stream>>>(ptrs, tcb, TOTAL_TEXELS);
        int total  = S * 8;
        int blocks = (total + 255) / 256;
        grid_main<<<blocks, 256, 0, stream>>>(coords, tcb, (f32x4*)d_out, S);
    } else if (levels == NLEVELS) {
        int total  = S * 8;
        int blocks = (total + 255) / 256;
        grid_main_direct<<<blocks, 256, 0, stream>>>(coords, ptrs, (float4*)d_out, S);
    } else {
        int blocks = (S + 255) / 256;
        grid_generic<<<blocks, 256, 0, stream>>>(coords, ptrs, (float4*)d_out, S, levels);
    }
}